// Round 13
// baseline (936.637 us; speedup 1.0000x reference)
//
#include <hip/hip_runtime.h>

// ---------------------------------------------------------------------------
// SelfAttention: B=1024, C=N=256.
//   Q=(WqX+bq)/16 ; K=WkX+bk ; Vg=gamma*(WvX+bv) ; P=softmax_rows(Q K^T);
//   out = Vg P + x
// R13 pipeline:
//   k_prep       : W3h[768][256] = bf16(scale_p * W_p), b3[768]
//   k_transpose2 : Xt[bn][i] = bf16(x[b][i][n])  AND  xh = bf16(x) row-major
//   k_gemm       : Y = W3h * Xt^T + b3, batch-major [b][3][256][256]
//   attn8        : attn7 structure at 256-VGPR cap (launch_bounds(512,1)):
//                  K quarter-staged (dbuf, overlapped with QK^T), exp(S) in
//                  regs, P^T in two 64KB n-halves, bf16 residual from xh.
// ---------------------------------------------------------------------------

typedef __attribute__((ext_vector_type(8))) short bf16x8;
typedef __attribute__((ext_vector_type(4))) short bf16x4;
typedef __attribute__((ext_vector_type(4))) float f32x4;

#define MFMA16(a, b, c) __builtin_amdgcn_mfma_f32_16x16x32_bf16((a), (b), (c), 0, 0, 0)

#define GLDS16(g, l)                                                      \
  __builtin_amdgcn_global_load_lds(                                       \
      (const __attribute__((address_space(1))) void*)(g),                 \
      (__attribute__((address_space(3))) void*)(l), 16, 0, 0)

static __device__ __forceinline__ unsigned short f2bf(float f) {
  unsigned int u = __float_as_uint(f);
  u += 0x7fffu + ((u >> 16) & 1u);  // round-to-nearest-even
  return (unsigned short)(u >> 16);
}

static __device__ __forceinline__ float bf2f(unsigned short s) {
  return __uint_as_float((unsigned int)s << 16);
}

// 512B-row swizzle (K quarters, gemm tiles)
static __device__ __forceinline__ int swz(int row, int byteInRow) {
  return row * 512 + (byteInRow ^ ((row & 7) << 4));
}
// 256B-row swizzle (P^T halves)
static __device__ __forceinline__ int swz256(int row, int byteInRow) {
  return row * 256 + (byteInRow ^ ((row & 7) << 4));
}

// ---------------------------------------------------------------------------
// Kernel 0: stacked scaled weights + biases.
// ---------------------------------------------------------------------------
__global__ void k_prep(const float* __restrict__ Wq, const float* __restrict__ bq,
                       const float* __restrict__ Wk, const float* __restrict__ bk,
                       const float* __restrict__ Wv, const float* __restrict__ bv,
                       const float* __restrict__ gamma,
                       unsigned short* __restrict__ W3h, float* __restrict__ b3) {
  const int r = blockIdx.x;  // 0..767
  const int p = r >> 8, sr = r & 255;
  const float s = (p == 0) ? 0.0625f : (p == 1 ? 1.0f : gamma[0]);
  const float* W = (p == 0) ? Wq : (p == 1 ? Wk : Wv);
  const float* bs = (p == 0) ? bq : (p == 1 ? bk : bv);
  W3h[r * 256 + threadIdx.x] = f2bf(W[sr * 256 + threadIdx.x] * s);
  if (threadIdx.x == 0) b3[r] = bs[sr] * s;
}

// ---------------------------------------------------------------------------
// Kernel 1: Xt[b*256 + n][i] = bf16(x[b][i][n])  and  xh[b][c][n] = bf16(x)
// ---------------------------------------------------------------------------
__global__ void k_transpose2(const float* __restrict__ x,
                             unsigned short* __restrict__ xt,
                             unsigned short* __restrict__ xh) {
  __shared__ float tile[64][65];
  const int b = blockIdx.x;
  const float* xb = x + (size_t)b * 65536;
  unsigned short* xtb = xt + (size_t)b * 65536;
  unsigned short* xhb = xh + (size_t)b * 65536;
  const int t = threadIdx.x, tx = t & 63, ty = t >> 6;
  const int cp = t & 31, rb = t >> 5;
  for (int tb = 0; tb < 16; ++tb) {
    const int c0 = (tb >> 2) * 64, n0 = (tb & 3) * 64;
    __syncthreads();
#pragma unroll
    for (int yy = 0; yy < 16; ++yy) {
      const int r = ty + yy * 4;
      tile[r][tx] = xb[(c0 + r) * 256 + n0 + tx];
    }
    __syncthreads();
    // row-major bf16 copy (coalesced 2B stores; conflict-free LDS reads)
#pragma unroll
    for (int yy = 0; yy < 16; ++yy) {
      const int r = ty + yy * 4;
      xhb[(c0 + r) * 256 + n0 + tx] = f2bf(tile[r][tx]);
    }
    // transposed bf16 (ushort2 stores)
#pragma unroll
    for (int yy = 0; yy < 8; ++yy) {
      const int nl = rb + yy * 8;
      ushort2 v;
      v.x = f2bf(tile[2 * cp][nl]);
      v.y = f2bf(tile[2 * cp + 1][nl]);
      *(ushort2*)(xtb + (n0 + nl) * 256 + c0 + 2 * cp) = v;
    }
  }
}

// ---------------------------------------------------------------------------
// Kernel 2: flat GEMM  Y[.] = W3h * Xt^T + b3, batch-major output.
// ---------------------------------------------------------------------------
__global__ __launch_bounds__(256, 4) void k_gemm(
    const unsigned short* __restrict__ W3h, const float* __restrict__ b3,
    const unsigned short* __restrict__ Xt, unsigned short* __restrict__ Y) {
  __shared__ char smem[32768];
  const int bid = blockIdx.x;
  const int swzb = (bid & 7) * 1536 + (bid >> 3);
  const int r_t = swzb % 6, bn_t = swzb / 6;
  const int m0 = r_t * 128, n0 = bn_t * 128;
  const int tid = threadIdx.x, wv = tid >> 6, lane = tid & 63;
  const int lo = lane & 15, hi = lane >> 4;
  const int wm = wv >> 1, wn = wv & 1;

  f32x4 acc[4][4];
#pragma unroll
  for (int i = 0; i < 4; ++i)
#pragma unroll
    for (int j = 0; j < 4; ++j) acc[i][j] = (f32x4){0.f, 0.f, 0.f, 0.f};

  for (int k0 = 0; k0 < 256; k0 += 64) {
#pragma unroll
    for (int j = 0; j < 4; ++j) {
      const int s = j * 256 + tid;
      const int row = s >> 3, gs = (s & 7) ^ (row & 7);
      GLDS16(W3h + (size_t)(m0 + row) * 256 + k0 + gs * 8,
             smem + j * 4096 + wv * 1024);
    }
#pragma unroll
    for (int j = 0; j < 4; ++j) {
      const int s = j * 256 + tid;
      const int row = s >> 3, gs = (s & 7) ^ (row & 7);
      GLDS16(Xt + (size_t)(n0 + row) * 256 + k0 + gs * 8,
             smem + 16384 + j * 4096 + wv * 1024);
    }
    __syncthreads();
#pragma unroll
    for (int kk = 0; kk < 2; ++kk) {
      bf16x8 a[4], b[4];
#pragma unroll
      for (int rt = 0; rt < 4; ++rt) {
        const int row = wm * 64 + rt * 16 + lo, g = kk * 4 + hi;
        a[rt] = *(const bf16x8*)(smem + row * 128 + ((g ^ (row & 7)) * 16));
      }
#pragma unroll
      for (int ct = 0; ct < 4; ++ct) {
        const int row = wn * 64 + ct * 16 + lo, g = kk * 4 + hi;
        b[ct] = *(const bf16x8*)(smem + 16384 + row * 128 + ((g ^ (row & 7)) * 16));
      }
#pragma unroll
      for (int rt = 0; rt < 4; ++rt)
#pragma unroll
        for (int ct = 0; ct < 4; ++ct) acc[rt][ct] = MFMA16(a[rt], b[ct], acc[rt][ct]);
    }
    __syncthreads();
  }

  float b3v[4][4];
#pragma unroll
  for (int rt = 0; rt < 4; ++rt)
#pragma unroll
    for (int reg = 0; reg < 4; ++reg)
      b3v[rt][reg] = b3[m0 + wm * 64 + rt * 16 + hi * 4 + reg];
#pragma unroll
  for (int rt = 0; rt < 4; ++rt)
#pragma unroll
    for (int ct = 0; ct < 4; ++ct)
#pragma unroll
      for (int reg = 0; reg < 4; ++reg) {
        const int m = wm * 64 + rt * 16 + hi * 4 + reg;
        const int n = wn * 64 + ct * 16 + lo;
        *(unsigned short*)(smem + m * 256 + ((n * 2) ^ ((m & 7) << 4))) =
            f2bf(acc[rt][ct][reg] + b3v[rt][reg]);
      }
  __syncthreads();
  const int p = m0 >> 8, sr0 = m0 & 255;
  const int bb = n0 >> 8, nl0 = n0 & 255;
  unsigned short* dstb = Y + (size_t)bb * 196608 + (size_t)p * 65536;
#pragma unroll
  for (int j = 0; j < 8; ++j) {
    const int s = j * 256 + tid;
    const int m = s >> 4, pp = s & 15;
    const int ng = pp ^ (m & 7);
    int4 v = *(const int4*)(smem + m * 256 + pp * 16);
    *(int4*)(dstb + (size_t)(sr0 + m) * 256 + nl0 + ng * 8) = v;
  }
}

// ---------------------------------------------------------------------------
// Kernel 3: attn8 — quarter-staged K, pk-in-regs, n-halved PV, bf16 residual.
//   launch_bounds(512,1): 256-VGPR cap so the ~250-VGPR live set fits.
// ---------------------------------------------------------------------------
__global__ __launch_bounds__(512, 1) void attn8(
    const unsigned short* __restrict__ xh, const unsigned short* __restrict__ Y,
    float* __restrict__ out) {
  __shared__ char smem[65536];  // K dbuf: [0,32K)+[32K,64K); later P^T 64KB
  const int b = blockIdx.x;
  const unsigned short* xhb = xh + (size_t)b * 65536;
  const unsigned short* Qb = Y + (size_t)b * 196608;
  const unsigned short* Kb = Qb + 65536;
  const unsigned short* Vb = Qb + 131072;
  const int tid = threadIdx.x, w = tid >> 6, lane = tid & 63;
  const int lo = lane & 15, hi = lane >> 4;
  const int r0 = w * 32;

#define STAGE_K(q, reg)                                                     \
  {                                                                         \
    _Pragma("unroll") for (int i = 0; i < 4; ++i) {                         \
      const int idx = i * 512 + tid;                                        \
      const int row = idx >> 5, c16 = idx & 31;                             \
      const int gs = (c16 & 24) | ((c16 ^ row) & 7);                        \
      GLDS16(Kb + (size_t)((q) * 64 + row) * 256 + gs * 8,                  \
             smem + (reg) * 32768 + idx * 16);                              \
    }                                                                       \
  }

  STAGE_K(0, 0)
  STAGE_K(1, 1)
  bf16x8 aq[2][8];
#pragma unroll
  for (int k0 = 0; k0 < 8; ++k0)
#pragma unroll
    for (int rt = 0; rt < 2; ++rt)
      aq[rt][k0] =
          *(const bf16x8*)(Qb + (size_t)(r0 + rt * 16 + lo) * 256 + k0 * 32 + hi * 8);
  __syncthreads();  // K0, K1, Q resident

  bf16x4 pk[4][2][4];  // unnormalized exp(S), [quarter][rt][ct]
  f32x4 lsum[2];
  lsum[0] = (f32x4){0.f, 0.f, 0.f, 0.f};
  lsum[1] = (f32x4){0.f, 0.f, 0.f, 0.f};

#define QUARTER(q, reg)                                                     \
  {                                                                         \
    const char* base = smem + (reg) * 32768;                                \
    f32x4 acc[2][4];                                                        \
    _Pragma("unroll") for (int i = 0; i < 2; ++i)                           \
        _Pragma("unroll") for (int j = 0; j < 4; ++j)                       \
            acc[i][j] = (f32x4){0.f, 0.f, 0.f, 0.f};                        \
    _Pragma("unroll") for (int k0 = 0; k0 < 8; ++k0)                        \
        _Pragma("unroll") for (int ct = 0; ct < 4; ++ct) {                  \
      bf16x8 bb = *(const bf16x8*)(base + swz(ct * 16 + lo,                 \
                                              (k0 * 32 + hi * 8) * 2));     \
      acc[0][ct] = MFMA16(aq[0][k0], bb, acc[0][ct]);                       \
      acc[1][ct] = MFMA16(aq[1][k0], bb, acc[1][ct]);                       \
    }                                                                       \
    _Pragma("unroll") for (int rt = 0; rt < 2; ++rt)                        \
        _Pragma("unroll") for (int ct = 0; ct < 4; ++ct) {                  \
      f32x4 p;                                                              \
      _Pragma("unroll") for (int reg2 = 0; reg2 < 4; ++reg2)                \
          p[reg2] = __expf(acc[rt][ct][reg2]);                              \
      lsum[rt] += p;                                                        \
      bf16x4 v;                                                             \
      _Pragma("unroll") for (int reg2 = 0; reg2 < 4; ++reg2)                \
          v[reg2] = (short)f2bf(p[reg2]);                                   \
      pk[q][rt][ct] = v;                                                    \
    }                                                                       \
  }

  QUARTER(0, 0)
  __syncthreads();
  STAGE_K(2, 0)
  QUARTER(1, 1)
  __syncthreads();
  STAGE_K(3, 1)
  QUARTER(2, 0)
  __syncthreads();
  QUARTER(3, 1)

  f32x4 inv[2];
#pragma unroll
  for (int rt = 0; rt < 2; ++rt)
#pragma unroll
    for (int reg = 0; reg < 4; ++reg) {
      float s = lsum[rt][reg];
      s += __shfl_xor(s, 1);
      s += __shfl_xor(s, 2);
      s += __shfl_xor(s, 4);
      s += __shfl_xor(s, 8);
      inv[rt][reg] = 1.0f / s;
    }
  __syncthreads();  // quarter-3 reads done before P^T overwrite

#define WRITE_PK                                                            \
  {                                                                         \
    _Pragma("unroll") for (int q = 0; q < 4; ++q)                           \
        _Pragma("unroll") for (int rt = 0; rt < 2; ++rt)                    \
            _Pragma("unroll") for (int ct = 0; ct < 4; ++ct) {              \
      const int d = q * 64 + ct * 16 + lo;                                  \
      const int cl = (w & 3) * 32 + rt * 16 + hi * 4;                       \
      bf16x4 src = pk[q][rt][ct];                                           \
      bf16x4 v;                                                             \
      _Pragma("unroll") for (int reg2 = 0; reg2 < 4; ++reg2)                \
          v[reg2] = (short)f2bf(bf2f((unsigned short)src[reg2]) *           \
                                inv[rt][reg2]);                             \
      *(bf16x4*)(smem + swz256(d, cl * 2)) = v;                             \
    }                                                                       \
  }

  const int rb0 = (w >> 1) * 64, d0 = (w & 1) * 128;
  f32x4 accB[4][8];
#pragma unroll
  for (int i = 0; i < 4; ++i)
#pragma unroll
    for (int j = 0; j < 8; ++j) accB[i][j] = (f32x4){0.f, 0.f, 0.f, 0.f};

#define PV_HALF(h)                                                          \
  {                                                                         \
    _Pragma("unroll") for (int k0 = 0; k0 < 4; ++k0) {                      \
      bf16x8 a[4];                                                          \
      _Pragma("unroll") for (int rt = 0; rt < 4; ++rt)                      \
          a[rt] = *(const bf16x8*)(Vb + (size_t)(rb0 + rt * 16 + lo) * 256  \
                                   + (h) * 128 + k0 * 32 + hi * 8);         \
      _Pragma("unroll") for (int ct = 0; ct < 8; ++ct) {                    \
        const int row = d0 + ct * 16 + lo;                                  \
        bf16x8 bb = *(const bf16x8*)(smem +                                 \
                                     swz256(row, k0 * 64 + hi * 16));       \
        _Pragma("unroll") for (int rt = 0; rt < 4; ++rt)                    \
            accB[rt][ct] = MFMA16(a[rt], bb, accB[rt][ct]);                 \
      }                                                                     \
    }                                                                       \
  }

  if (w < 4) WRITE_PK
  __syncthreads();
  PV_HALF(0)
  __syncthreads();
  if (w >= 4) WRITE_PK
  __syncthreads();
  PV_HALF(1)

  // ---- epilogue: out = O + bf16(x) ----
  float* ob = out + (size_t)b * 65536;
#pragma unroll
  for (int rt = 0; rt < 4; ++rt)
#pragma unroll
    for (int reg = 0; reg < 4; ++reg) {
      const int c = rb0 + rt * 16 + hi * 4 + reg;
#pragma unroll
      for (int ct = 0; ct < 8; ++ct) {
        const int d = d0 + ct * 16 + lo;
        const int idx = c * 256 + d;
        ob[idx] = accB[rt][ct][reg] + bf2f(xhb[idx]);
      }
    }
}

// ---------------------------------------------------------------------------
extern "C" void kernel_launch(void* const* d_in, const int* in_sizes, int n_in,
                              void* d_out, int out_size, void* d_ws, size_t ws_size,
                              hipStream_t stream) {
  const float* x = (const float*)d_in[0];
  const float* Wq = (const float*)d_in[1];
  const float* bq = (const float*)d_in[2];
  const float* Wk = (const float*)d_in[3];
  const float* bk = (const float*)d_in[4];
  const float* Wv = (const float*)d_in[5];
  const float* bv = (const float*)d_in[6];
  const float* gamma = (const float*)d_in[7];
  float* out = (float*)d_out;

  unsigned short* Y = (unsigned short*)d_ws;                 // 384 MiB
  unsigned short* Xt = Y + (size_t)1024 * 196608;            // 128 MiB
  unsigned short* xh = Xt + (size_t)1024 * 65536;            // 128 MiB
  unsigned short* W3h = xh + (size_t)1024 * 65536;           // 384 KiB
  float* b3 = (float*)(W3h + 768 * 256);                     // 3 KiB
  const size_t need =
      ((size_t)1024 * 196608 + 2 * (size_t)1024 * 65536 + 768 * 256) * 2 + 768 * 4;
  if (ws_size < need) return;  // ~640.4 MiB

  hipLaunchKernelGGL(k_prep, dim3(768), dim3(256), 0, stream,
                     Wq, bq, Wk, bk, Wv, bv, gamma, W3h, b3);
  hipLaunchKernelGGL(k_transpose2, dim3(1024), dim3(256), 0, stream, x, Xt, xh);
  hipLaunchKernelGGL(k_gemm, dim3(12288), dim3(256), 0, stream, W3h, b3, Xt, Y);
  hipLaunchKernelGGL(attn8, dim3(1024), dim3(512), 0, stream, xh, Y, out);
}

// Round 14
// 695.185 us; speedup vs baseline: 1.3473x; 1.3473x over previous
//
#include <hip/hip_runtime.h>

// ---------------------------------------------------------------------------
// SelfAttention: B=1024, C=N=256.
//   Q=(WqX+bq)/16 ; K=WkX+bk ; Vg=gamma*(WvX+bv) ; P=softmax_rows(Q K^T);
//   out = Vg P + x
// R14 pipeline (= R8 best config + bf16 residual side-product):
//   k_prep  : W3h[768][256] = bf16(scale_p * W_p), b3[768]
//   k_gemm2 : Y = W3h * X^T + b3, batch-major [b][3][256][256]; fused x
//             transpose; r_t==0 blocks also emit xh = bf16(x) (each x chunk
//             is already in registers during staging).
//   attn5   : single-pass fused attention + V-prefetch; residual from xh
//             (128 MB bf16 instead of 256 MB f32).
// ---------------------------------------------------------------------------

typedef __attribute__((ext_vector_type(8))) short bf16x8;
typedef __attribute__((ext_vector_type(4))) short bf16x4;
typedef __attribute__((ext_vector_type(4))) float f32x4;

#define MFMA16(a, b, c) __builtin_amdgcn_mfma_f32_16x16x32_bf16((a), (b), (c), 0, 0, 0)

#define GLDS16(g, l)                                                      \
  __builtin_amdgcn_global_load_lds(                                       \
      (const __attribute__((address_space(1))) void*)(g),                 \
      (__attribute__((address_space(3))) void*)(l), 16, 0, 0)

static __device__ __forceinline__ unsigned short f2bf(float f) {
  unsigned int u = __float_as_uint(f);
  u += 0x7fffu + ((u >> 16) & 1u);  // round-to-nearest-even
  return (unsigned short)(u >> 16);
}

static __device__ __forceinline__ float bf2f(unsigned short s) {
  return __uint_as_float((unsigned int)s << 16);
}

// rows x 512B swizzled LDS buffer; XOR spreads stride-512B accesses.
static __device__ __forceinline__ int swz(int row, int byteInRow) {
  return row * 512 + (byteInRow ^ ((row & 7) << 4));
}

// ---------------------------------------------------------------------------
// Kernel 0: stacked scaled weights + biases.
// ---------------------------------------------------------------------------
__global__ void k_prep(const float* __restrict__ Wq, const float* __restrict__ bq,
                       const float* __restrict__ Wk, const float* __restrict__ bk,
                       const float* __restrict__ Wv, const float* __restrict__ bv,
                       const float* __restrict__ gamma,
                       unsigned short* __restrict__ W3h, float* __restrict__ b3) {
  const int r = blockIdx.x;  // 0..767
  const int p = r >> 8, sr = r & 255;
  const float s = (p == 0) ? 0.0625f : (p == 1 ? 1.0f : gamma[0]);
  const float* W = (p == 0) ? Wq : (p == 1 ? Wk : Wv);
  const float* bs = (p == 0) ? bq : (p == 1 ? bk : bv);
  W3h[r * 256 + threadIdx.x] = f2bf(W[sr * 256 + threadIdx.x] * s);
  if (threadIdx.x == 0) b3[r] = bs[sr] * s;
}

// ---------------------------------------------------------------------------
// Kernel 1: flat GEMM with fused transpose (R8 kernel + xh side-product).
//   Y[m][b*256+n] = sum_i W3h[m][i] * x[b][i][n] + b3[m]
//   128x128 tile, BK=64, 256 threads, LDS: A 16K | B 16K | TS 17K = 49K
// ---------------------------------------------------------------------------
__global__ __launch_bounds__(256, 3) void k_gemm2(
    const unsigned short* __restrict__ W3h, const float* __restrict__ b3,
    const float* __restrict__ x, unsigned short* __restrict__ Y,
    unsigned short* __restrict__ xh) {
  __shared__ char smem[50176];
  float* TS = (float*)(smem + 32768);
  const int bid = blockIdx.x;
  const int swzb = (bid & 7) * 1536 + (bid >> 3);
  const int r_t = swzb % 6, bn_t = swzb / 6;
  const int m0 = r_t * 128, n0 = bn_t * 128;
  const int bb = n0 >> 8, nl0 = n0 & 255;
  const float* xb = x + (size_t)bb * 65536;
  unsigned short* xhb = xh + (size_t)bb * 65536;
  const int tid = threadIdx.x, wv = tid >> 6, lane = tid & 63;
  const int lo = lane & 15, hi = lane >> 4;
  const int wm = wv >> 1, wn = wv & 1;
  const int tr = tid >> 4, tc = (tid & 15) * 4;  // staging row/col

  f32x4 acc[4][4];
#pragma unroll
  for (int i = 0; i < 4; ++i)
#pragma unroll
    for (int j = 0; j < 4; ++j) acc[i][j] = (f32x4){0.f, 0.f, 0.f, 0.f};

  for (int k0 = 0; k0 < 256; k0 += 64) {
    // ---- A tile via GLDS (async, drained by first barrier below) ----
#pragma unroll
    for (int j = 0; j < 4; ++j) {
      const int s = j * 256 + tid;
      const int row = s >> 3, gs = (s & 7) ^ (row & 7);
      GLDS16(W3h + (size_t)(m0 + row) * 256 + k0 + gs * 8,
             smem + j * 4096 + wv * 1024);
    }

    // ---- B staging: two 64x64 transpose chunks through TS ----
#pragma unroll
    for (int c = 0; c < 2; ++c) {
      if (c == 1) __syncthreads();  // chunk0 TS reads done before overwrite
#pragma unroll
      for (int j = 0; j < 4; ++j) {
        const int row = k0 + tr + j * 16;
        const int col = nl0 + c * 64 + tc;
        float4 xg = *(const float4*)(xb + row * 256 + col);
        *(float4*)(&TS[(tr + j * 16) * 68 + tc]) = xg;
        if (r_t == 0) {  // emit bf16(x) once per (batch, col-chunk)
          ushort4 h;
          h.x = f2bf(xg.x);
          h.y = f2bf(xg.y);
          h.z = f2bf(xg.z);
          h.w = f2bf(xg.w);
          *(ushort4*)(xhb + (size_t)row * 256 + col) = h;
        }
      }
      __syncthreads();  // TS visible
#pragma unroll
      for (int ff = 0; ff < 2; ++ff) {
        const int g = wv + ff * 4;  // k-granule 0..7
        const int n = lane;
        bf16x8 v;
#pragma unroll
        for (int j = 0; j < 8; ++j) v[j] = (short)f2bf(TS[(g * 8 + j) * 68 + n]);
        const int row = c * 64 + n;
        *(bf16x8*)(smem + 16384 + row * 128 + ((g ^ (row & 7)) * 16)) = v;
      }
    }
    __syncthreads();  // B-tile writes visible (A-tile long drained)

    // ---- MFMA ----
#pragma unroll
    for (int kk = 0; kk < 2; ++kk) {
      bf16x8 a[4], b[4];
#pragma unroll
      for (int rt = 0; rt < 4; ++rt) {
        const int row = wm * 64 + rt * 16 + lo, g = kk * 4 + hi;
        a[rt] = *(const bf16x8*)(smem + row * 128 + ((g ^ (row & 7)) * 16));
      }
#pragma unroll
      for (int ct = 0; ct < 4; ++ct) {
        const int row = wn * 64 + ct * 16 + lo, g = kk * 4 + hi;
        b[ct] = *(const bf16x8*)(smem + 16384 + row * 128 + ((g ^ (row & 7)) * 16));
      }
#pragma unroll
      for (int rt = 0; rt < 4; ++rt)
#pragma unroll
        for (int ct = 0; ct < 4; ++ct) acc[rt][ct] = MFMA16(a[rt], b[ct], acc[rt][ct]);
    }
    __syncthreads();  // MFMA reads done before next k0 overwrite
  }

  // Epilogue: bias, bf16, swizzled-LDS repack, coalesced 16B batch-major stores.
  float b3v[4][4];
#pragma unroll
  for (int rt = 0; rt < 4; ++rt)
#pragma unroll
    for (int reg = 0; reg < 4; ++reg)
      b3v[rt][reg] = b3[m0 + wm * 64 + rt * 16 + hi * 4 + reg];
#pragma unroll
  for (int rt = 0; rt < 4; ++rt)
#pragma unroll
    for (int ct = 0; ct < 4; ++ct)
#pragma unroll
      for (int reg = 0; reg < 4; ++reg) {
        const int m = wm * 64 + rt * 16 + hi * 4 + reg;
        const int n = wn * 64 + ct * 16 + lo;
        *(unsigned short*)(smem + m * 256 + ((n * 2) ^ ((m & 7) << 4))) =
            f2bf(acc[rt][ct][reg] + b3v[rt][reg]);
      }
  __syncthreads();
  const int p = m0 >> 8, sr0 = m0 & 255;
  unsigned short* dstb = Y + (size_t)bb * 196608 + (size_t)p * 65536;
#pragma unroll
  for (int j = 0; j < 8; ++j) {
    const int s = j * 256 + tid;
    const int m = s >> 4, pp = s & 15;
    const int ng = pp ^ (m & 7);
    int4 v = *(const int4*)(smem + m * 256 + pp * 16);
    *(int4*)(dstb + (size_t)(sr0 + m) * 256 + nl0 + ng * 8) = v;
  }
}

// ---------------------------------------------------------------------------
// Kernel 2: single-pass fused attention (128 KB LDS, 1 block/CU) — R8 kernel,
//   residual from bf16 xh.
//   K staged once via global_load_lds; Q prefetched to regs during staging;
//   V half-prefetched under the softmax shadow; max-skip softmax;
//   P^T -> LDS (overwrites K); O full-width + residual.
// ---------------------------------------------------------------------------
__global__ __launch_bounds__(512, 2) void attn5(
    const unsigned short* __restrict__ xh, const unsigned short* __restrict__ Y,
    float* __restrict__ out) {
  __shared__ char smem[131072];  // 256 rows x 512 B
  const int b = blockIdx.x;
  const unsigned short* xhb = xh + (size_t)b * 65536;
  const unsigned short* Qb = Y + (size_t)b * 196608;
  const unsigned short* Kb = Qb + 65536;
  const unsigned short* Vb = Qb + 131072;
  const int tid = threadIdx.x, w = tid >> 6, lane = tid & 63;
  const int lo = lane & 15, hi = lane >> 4;
  const int r0 = w * 32;
  const int rb0 = (w >> 1) * 64, d0 = (w & 1) * 128;

  // ---- issue async K stage (linear LDS dest, inverse-swizzled source) ----
#pragma unroll
  for (int i = 0; i < 16; ++i) {
    const int idx = i * 512 + tid;  // 16B granules, 0..8191
    const int row = idx >> 5, c16 = idx & 31;
    const int gs = (c16 & 24) | ((c16 ^ row) & 7);
    GLDS16(Kb + (size_t)row * 256 + gs * 8, smem + idx * 16);
  }
  // ---- concurrently prefetch this wave's Q fragments into registers ----
  bf16x8 aq[2][8];
#pragma unroll
  for (int k0 = 0; k0 < 8; ++k0)
#pragma unroll
    for (int rt = 0; rt < 2; ++rt)
      aq[rt][k0] =
          *(const bf16x8*)(Qb + (size_t)(r0 + rt * 16 + lo) * 256 + k0 * 32 + hi * 8);
  __syncthreads();

  bf16x8 av[4][4];  // V prefetch (k = 0..127), issued under softmax shadow

  // ---- Phase A: S = Q K^T (regs x LDS); p=exp(S); normalize; P^T -> LDS ----
  {
    f32x4 acc[2][16];
#pragma unroll
    for (int i = 0; i < 2; ++i)
#pragma unroll
      for (int j = 0; j < 16; ++j) acc[i][j] = (f32x4){0.f, 0.f, 0.f, 0.f};
#pragma unroll
    for (int k0 = 0; k0 < 8; ++k0)
#pragma unroll
      for (int ct = 0; ct < 16; ++ct) {
        bf16x8 bb = *(const bf16x8*)(smem + swz(ct * 16 + lo, (k0 * 32 + hi * 8) * 2));
        acc[0][ct] = MFMA16(aq[0][k0], bb, acc[0][ct]);
        acc[1][ct] = MFMA16(aq[1][k0], bb, acc[1][ct]);
      }
    // V half-prefetch: HBM stays busy under the softmax + P^T write + barrier
#pragma unroll
    for (int kq = 0; kq < 4; ++kq)
#pragma unroll
      for (int rt = 0; rt < 4; ++rt)
        av[rt][kq] =
            *(const bf16x8*)(Vb + (size_t)(rb0 + rt * 16 + lo) * 256 + kq * 32 + hi * 8);
    // max-skip softmax: p = exp(S); row-sum over 16 ct + 16 lo-lanes
#pragma unroll
    for (int rt = 0; rt < 2; ++rt)
#pragma unroll
      for (int reg = 0; reg < 4; ++reg) {
        float s = 0.f;
        float vals[16];
#pragma unroll
        for (int ct = 0; ct < 16; ++ct) {
          const float p = __expf(acc[rt][ct][reg]);
          vals[ct] = p;
          s += p;
        }
        s += __shfl_xor(s, 1);
        s += __shfl_xor(s, 2);
        s += __shfl_xor(s, 4);
        s += __shfl_xor(s, 8);
        const float inv = 1.0f / s;
#pragma unroll
        for (int ct = 0; ct < 16; ++ct) acc[rt][ct][reg] = vals[ct] * inv;
      }
    __syncthreads();  // all K reads done before overwrite
#pragma unroll
    for (int rt = 0; rt < 2; ++rt)
#pragma unroll
      for (int ct = 0; ct < 16; ++ct) {
        const int d = ct * 16 + lo;
        const int s0 = r0 + rt * 16 + hi * 4;
        bf16x4 v;
#pragma unroll
        for (int reg = 0; reg < 4; ++reg) v[reg] = (short)f2bf(acc[rt][ct][reg]);
        *(bf16x4*)(smem + swz(d, s0 * 2)) = v;
      }
  }
  __syncthreads();

  // ---- Phase B: O = V P ; out = O + bf16(x) ----
  {
    f32x4 acc[4][8];
#pragma unroll
    for (int i = 0; i < 4; ++i)
#pragma unroll
      for (int j = 0; j < 8; ++j) acc[i][j] = (f32x4){0.f, 0.f, 0.f, 0.f};
    // first half: V from prefetched registers
#pragma unroll
    for (int k0 = 0; k0 < 4; ++k0)
#pragma unroll
      for (int ct = 0; ct < 8; ++ct) {
        bf16x8 bb = *(const bf16x8*)(smem + swz(d0 + ct * 16 + lo, (k0 * 32 + hi * 8) * 2));
#pragma unroll
        for (int rt = 0; rt < 4; ++rt) acc[rt][ct] = MFMA16(av[rt][k0], bb, acc[rt][ct]);
      }
    // second half: V loaded in-loop (compiler hoists into first half's MFMA)
#pragma unroll
    for (int k0 = 4; k0 < 8; ++k0) {
      bf16x8 a[4];
#pragma unroll
      for (int rt = 0; rt < 4; ++rt)
        a[rt] = *(const bf16x8*)(Vb + (size_t)(rb0 + rt * 16 + lo) * 256 + k0 * 32 + hi * 8);
#pragma unroll
      for (int ct = 0; ct < 8; ++ct) {
        bf16x8 bb = *(const bf16x8*)(smem + swz(d0 + ct * 16 + lo, (k0 * 32 + hi * 8) * 2));
#pragma unroll
        for (int rt = 0; rt < 4; ++rt) acc[rt][ct] = MFMA16(a[rt], bb, acc[rt][ct]);
      }
    }
    float* ob = out + (size_t)b * 65536;
#pragma unroll
    for (int rt = 0; rt < 4; ++rt)
#pragma unroll
      for (int reg = 0; reg < 4; ++reg) {
        const int c = rb0 + rt * 16 + hi * 4 + reg;
#pragma unroll
        for (int ct = 0; ct < 8; ++ct) {
          const int d = d0 + ct * 16 + lo;
          const int idx = c * 256 + d;
          ob[idx] = acc[rt][ct][reg] + bf2f(xhb[idx]);
        }
      }
  }
}

// ---------------------------------------------------------------------------
extern "C" void kernel_launch(void* const* d_in, const int* in_sizes, int n_in,
                              void* d_out, int out_size, void* d_ws, size_t ws_size,
                              hipStream_t stream) {
  const float* x = (const float*)d_in[0];
  const float* Wq = (const float*)d_in[1];
  const float* bq = (const float*)d_in[2];
  const float* Wk = (const float*)d_in[3];
  const float* bk = (const float*)d_in[4];
  const float* Wv = (const float*)d_in[5];
  const float* bv = (const float*)d_in[6];
  const float* gamma = (const float*)d_in[7];
  float* out = (float*)d_out;

  unsigned short* Y = (unsigned short*)d_ws;                 // 384 MiB
  unsigned short* xh = Y + (size_t)1024 * 196608;            // 128 MiB
  unsigned short* W3h = xh + (size_t)1024 * 65536;           // 384 KiB
  float* b3 = (float*)(W3h + 768 * 256);                     // 3 KiB
  const size_t need =
      ((size_t)1024 * 196608 + (size_t)1024 * 65536 + 768 * 256) * 2 + 768 * 4;
  if (ws_size < need) return;  // ~512.4 MiB

  hipLaunchKernelGGL(k_prep, dim3(768), dim3(256), 0, stream,
                     Wq, bq, Wk, bk, Wv, bv, gamma, W3h, b3);
  hipLaunchKernelGGL(k_gemm2, dim3(12288), dim3(256), 0, stream, W3h, b3, x, Y, xh);
  hipLaunchKernelGGL(attn5, dim3(1024), dim3(512), 0, stream, xh, Y, out);
}

// Round 15
// 535.972 us; speedup vs baseline: 1.7475x; 1.2971x over previous
//
#include <hip/hip_runtime.h>

// ---------------------------------------------------------------------------
// SelfAttention: B=1024, C=N=256.
//   Q=(WqX+bq)/16 ; K=WkX+bk ; Vg=gamma*(WvX+bv) ; P=softmax_rows(Q K^T);
//   out = Vg P + x
// R15 pipeline (= R8 gemm2 k-loop verbatim + xh in epilogue + attn5-xh):
//   k_prep  : W3h[768][256] = bf16(scale_p * W_p), b3[768]
//   k_gemm2 : Y = W3h * X^T + b3, batch-major; fused x transpose (R8 k-loop,
//             untouched). r_t==0 blocks re-read their warm x-chunk in the
//             EPILOGUE (after all barriers) and emit xh = bf16(x).
//   attn5   : single-pass fused attention + V-prefetch; residual from xh.
// ---------------------------------------------------------------------------

typedef __attribute__((ext_vector_type(8))) short bf16x8;
typedef __attribute__((ext_vector_type(4))) short bf16x4;
typedef __attribute__((ext_vector_type(4))) float f32x4;

#define MFMA16(a, b, c) __builtin_amdgcn_mfma_f32_16x16x32_bf16((a), (b), (c), 0, 0, 0)

#define GLDS16(g, l)                                                      \
  __builtin_amdgcn_global_load_lds(                                       \
      (const __attribute__((address_space(1))) void*)(g),                 \
      (__attribute__((address_space(3))) void*)(l), 16, 0, 0)

static __device__ __forceinline__ unsigned short f2bf(float f) {
  unsigned int u = __float_as_uint(f);
  u += 0x7fffu + ((u >> 16) & 1u);  // round-to-nearest-even
  return (unsigned short)(u >> 16);
}

static __device__ __forceinline__ float bf2f(unsigned short s) {
  return __uint_as_float((unsigned int)s << 16);
}

// rows x 512B swizzled LDS buffer; XOR spreads stride-512B accesses.
static __device__ __forceinline__ int swz(int row, int byteInRow) {
  return row * 512 + (byteInRow ^ ((row & 7) << 4));
}

// ---------------------------------------------------------------------------
// Kernel 0: stacked scaled weights + biases.
// ---------------------------------------------------------------------------
__global__ void k_prep(const float* __restrict__ Wq, const float* __restrict__ bq,
                       const float* __restrict__ Wk, const float* __restrict__ bk,
                       const float* __restrict__ Wv, const float* __restrict__ bv,
                       const float* __restrict__ gamma,
                       unsigned short* __restrict__ W3h, float* __restrict__ b3) {
  const int r = blockIdx.x;  // 0..767
  const int p = r >> 8, sr = r & 255;
  const float s = (p == 0) ? 0.0625f : (p == 1 ? 1.0f : gamma[0]);
  const float* W = (p == 0) ? Wq : (p == 1 ? Wk : Wv);
  const float* bs = (p == 0) ? bq : (p == 1 ? bk : bv);
  W3h[r * 256 + threadIdx.x] = f2bf(W[sr * 256 + threadIdx.x] * s);
  if (threadIdx.x == 0) b3[r] = bs[sr] * s;
}

// ---------------------------------------------------------------------------
// Kernel 1: flat GEMM with fused transpose (R8 k-loop verbatim).
//   Y[m][b*256+n] = sum_i W3h[m][i] * x[b][i][n] + b3[m]
//   128x128 tile, BK=64, 256 threads, LDS: A 16K | B 16K | TS 17K = 49K
//   Epilogue (r_t==0 only): re-read warm x chunk, emit xh = bf16(x).
// ---------------------------------------------------------------------------
__global__ __launch_bounds__(256, 3) void k_gemm2(
    const unsigned short* __restrict__ W3h, const float* __restrict__ b3,
    const float* __restrict__ x, unsigned short* __restrict__ Y,
    unsigned short* __restrict__ xh) {
  __shared__ char smem[50176];
  float* TS = (float*)(smem + 32768);
  const int bid = blockIdx.x;
  const int swzb = (bid & 7) * 1536 + (bid >> 3);
  const int r_t = swzb % 6, bn_t = swzb / 6;
  const int m0 = r_t * 128, n0 = bn_t * 128;
  const int bb = n0 >> 8, nl0 = n0 & 255;
  const float* xb = x + (size_t)bb * 65536;
  const int tid = threadIdx.x, wv = tid >> 6, lane = tid & 63;
  const int lo = lane & 15, hi = lane >> 4;
  const int wm = wv >> 1, wn = wv & 1;
  const int tr = tid >> 4, tc = (tid & 15) * 4;  // staging row/col

  f32x4 acc[4][4];
#pragma unroll
  for (int i = 0; i < 4; ++i)
#pragma unroll
    for (int j = 0; j < 4; ++j) acc[i][j] = (f32x4){0.f, 0.f, 0.f, 0.f};

  for (int k0 = 0; k0 < 256; k0 += 64) {
    // ---- A tile via GLDS (async, drained by first barrier below) ----
#pragma unroll
    for (int j = 0; j < 4; ++j) {
      const int s = j * 256 + tid;
      const int row = s >> 3, gs = (s & 7) ^ (row & 7);
      GLDS16(W3h + (size_t)(m0 + row) * 256 + k0 + gs * 8,
             smem + j * 4096 + wv * 1024);
    }

    // ---- B staging: two 64x64 transpose chunks through TS ----
#pragma unroll
    for (int c = 0; c < 2; ++c) {
      if (c == 1) __syncthreads();  // chunk0 TS reads done before overwrite
      // load this chunk's x and write straight to TS (no barrier-crossing regs)
#pragma unroll
      for (int j = 0; j < 4; ++j) {
        float4 xg = *(const float4*)(xb + (k0 + tr + j * 16) * 256 + nl0 + c * 64 + tc);
        *(float4*)(&TS[(tr + j * 16) * 68 + tc]) = xg;
      }
      __syncthreads();  // TS visible
#pragma unroll
      for (int ff = 0; ff < 2; ++ff) {
        const int g = wv + ff * 4;  // k-granule 0..7
        const int n = lane;
        bf16x8 v;
#pragma unroll
        for (int j = 0; j < 8; ++j) v[j] = (short)f2bf(TS[(g * 8 + j) * 68 + n]);
        const int row = c * 64 + n;
        *(bf16x8*)(smem + 16384 + row * 128 + ((g ^ (row & 7)) * 16)) = v;
      }
    }
    __syncthreads();  // B-tile writes visible (A-tile long drained)

    // ---- MFMA ----
#pragma unroll
    for (int kk = 0; kk < 2; ++kk) {
      bf16x8 a[4], b[4];
#pragma unroll
      for (int rt = 0; rt < 4; ++rt) {
        const int row = wm * 64 + rt * 16 + lo, g = kk * 4 + hi;
        a[rt] = *(const bf16x8*)(smem + row * 128 + ((g ^ (row & 7)) * 16));
      }
#pragma unroll
      for (int ct = 0; ct < 4; ++ct) {
        const int row = wn * 64 + ct * 16 + lo, g = kk * 4 + hi;
        b[ct] = *(const bf16x8*)(smem + 16384 + row * 128 + ((g ^ (row & 7)) * 16));
      }
#pragma unroll
      for (int rt = 0; rt < 4; ++rt)
#pragma unroll
        for (int ct = 0; ct < 4; ++ct) acc[rt][ct] = MFMA16(a[rt], b[ct], acc[rt][ct]);
    }
    __syncthreads();  // MFMA reads done before next k0 overwrite
  }

  // Epilogue: bias, bf16, swizzled-LDS repack, coalesced 16B batch-major stores.
  float b3v[4][4];
#pragma unroll
  for (int rt = 0; rt < 4; ++rt)
#pragma unroll
    for (int reg = 0; reg < 4; ++reg)
      b3v[rt][reg] = b3[m0 + wm * 64 + rt * 16 + hi * 4 + reg];
#pragma unroll
  for (int rt = 0; rt < 4; ++rt)
#pragma unroll
    for (int ct = 0; ct < 4; ++ct)
#pragma unroll
      for (int reg = 0; reg < 4; ++reg) {
        const int m = wm * 64 + rt * 16 + hi * 4 + reg;
        const int n = wn * 64 + ct * 16 + lo;
        *(unsigned short*)(smem + m * 256 + ((n * 2) ^ ((m & 7) << 4))) =
            f2bf(acc[rt][ct][reg] + b3v[rt][reg]);
      }
  __syncthreads();
  const int p = m0 >> 8, sr0 = m0 & 255;
  unsigned short* dstb = Y + (size_t)bb * 196608 + (size_t)p * 65536;
#pragma unroll
  for (int j = 0; j < 8; ++j) {
    const int s = j * 256 + tid;
    const int m = s >> 4, pp = s & 15;
    const int ng = pp ^ (m & 7);
    int4 v = *(const int4*)(smem + m * 256 + pp * 16);
    *(int4*)(dstb + (size_t)(sr0 + m) * 256 + nl0 + ng * 8) = v;
  }

  // ---- xh emission (r_t==0 blocks only): warm re-read of the x chunk ----
  if (r_t == 0) {
    unsigned short* xhb = xh + (size_t)bb * 65536;
#pragma unroll
    for (int it = 0; it < 32; ++it) {
      const int s = it * 256 + tid;   // 0..8191 float4 granules
      const int row = s >> 5;         // 0..255
      const int c4 = (s & 31) * 4;    // 0..124
      float4 xg = *(const float4*)(xb + (size_t)row * 256 + nl0 + c4);
      ushort4 h;
      h.x = f2bf(xg.x);
      h.y = f2bf(xg.y);
      h.z = f2bf(xg.z);
      h.w = f2bf(xg.w);
      *(ushort4*)(xhb + (size_t)row * 256 + nl0 + c4) = h;
    }
  }
}

// ---------------------------------------------------------------------------
// Kernel 2: single-pass fused attention (128 KB LDS, 1 block/CU) — R8 kernel,
//   residual from bf16 xh.
// ---------------------------------------------------------------------------
__global__ __launch_bounds__(512, 2) void attn5(
    const unsigned short* __restrict__ xh, const unsigned short* __restrict__ Y,
    float* __restrict__ out) {
  __shared__ char smem[131072];  // 256 rows x 512 B
  const int b = blockIdx.x;
  const unsigned short* xhb = xh + (size_t)b * 65536;
  const unsigned short* Qb = Y + (size_t)b * 196608;
  const unsigned short* Kb = Qb + 65536;
  const unsigned short* Vb = Qb + 131072;
  const int tid = threadIdx.x, w = tid >> 6, lane = tid & 63;
  const int lo = lane & 15, hi = lane >> 4;
  const int r0 = w * 32;
  const int rb0 = (w >> 1) * 64, d0 = (w & 1) * 128;

  // ---- issue async K stage (linear LDS dest, inverse-swizzled source) ----
#pragma unroll
  for (int i = 0; i < 16; ++i) {
    const int idx = i * 512 + tid;  // 16B granules, 0..8191
    const int row = idx >> 5, c16 = idx & 31;
    const int gs = (c16 & 24) | ((c16 ^ row) & 7);
    GLDS16(Kb + (size_t)row * 256 + gs * 8, smem + idx * 16);
  }
  // ---- concurrently prefetch this wave's Q fragments into registers ----
  bf16x8 aq[2][8];
#pragma unroll
  for (int k0 = 0; k0 < 8; ++k0)
#pragma unroll
    for (int rt = 0; rt < 2; ++rt)
      aq[rt][k0] =
          *(const bf16x8*)(Qb + (size_t)(r0 + rt * 16 + lo) * 256 + k0 * 32 + hi * 8);
  __syncthreads();

  bf16x8 av[4][4];  // V prefetch (k = 0..127), issued under softmax shadow

  // ---- Phase A: S = Q K^T (regs x LDS); p=exp(S); normalize; P^T -> LDS ----
  {
    f32x4 acc[2][16];
#pragma unroll
    for (int i = 0; i < 2; ++i)
#pragma unroll
      for (int j = 0; j < 16; ++j) acc[i][j] = (f32x4){0.f, 0.f, 0.f, 0.f};
#pragma unroll
    for (int k0 = 0; k0 < 8; ++k0)
#pragma unroll
      for (int ct = 0; ct < 16; ++ct) {
        bf16x8 bb = *(const bf16x8*)(smem + swz(ct * 16 + lo, (k0 * 32 + hi * 8) * 2));
        acc[0][ct] = MFMA16(aq[0][k0], bb, acc[0][ct]);
        acc[1][ct] = MFMA16(aq[1][k0], bb, acc[1][ct]);
      }
    // V half-prefetch: HBM stays busy under the softmax + P^T write + barrier
#pragma unroll
    for (int kq = 0; kq < 4; ++kq)
#pragma unroll
      for (int rt = 0; rt < 4; ++rt)
        av[rt][kq] =
            *(const bf16x8*)(Vb + (size_t)(rb0 + rt * 16 + lo) * 256 + kq * 32 + hi * 8);
    // max-skip softmax: p = exp(S); row-sum over 16 ct + 16 lo-lanes
#pragma unroll
    for (int rt = 0; rt < 2; ++rt)
#pragma unroll
      for (int reg = 0; reg < 4; ++reg) {
        float s = 0.f;
        float vals[16];
#pragma unroll
        for (int ct = 0; ct < 16; ++ct) {
          const float p = __expf(acc[rt][ct][reg]);
          vals[ct] = p;
          s += p;
        }
        s += __shfl_xor(s, 1);
        s += __shfl_xor(s, 2);
        s += __shfl_xor(s, 4);
        s += __shfl_xor(s, 8);
        const float inv = 1.0f / s;
#pragma unroll
        for (int ct = 0; ct < 16; ++ct) acc[rt][ct][reg] = vals[ct] * inv;
      }
    __syncthreads();  // all K reads done before overwrite
#pragma unroll
    for (int rt = 0; rt < 2; ++rt)
#pragma unroll
      for (int ct = 0; ct < 16; ++ct) {
        const int d = ct * 16 + lo;
        const int s0 = r0 + rt * 16 + hi * 4;
        bf16x4 v;
#pragma unroll
        for (int reg = 0; reg < 4; ++reg) v[reg] = (short)f2bf(acc[rt][ct][reg]);
        *(bf16x4*)(smem + swz(d, s0 * 2)) = v;
      }
  }
  __syncthreads();

  // ---- Phase B: O = V P ; out = O + bf16(x) ----
  {
    f32x4 acc[4][8];
#pragma unroll
    for (int i = 0; i < 4; ++i)
#pragma unroll
      for (int j = 0; j < 8; ++j) acc[i][j] = (f32x4){0.f, 0.f, 0.f, 0.f};
    // first half: V from prefetched registers
#pragma unroll
    for (int k0 = 0; k0 < 4; ++k0)
#pragma unroll
      for (int ct = 0; ct < 8; ++ct) {
        bf16x8 bb = *(const bf16x8*)(smem + swz(d0 + ct * 16 + lo, (k0 * 32 + hi * 8) * 2));
#pragma unroll
        for (int rt = 0; rt < 4; ++rt) acc[rt][ct] = MFMA16(av[rt][k0], bb, acc[rt][ct]);
      }
    // second half: V loaded in-loop (compiler hoists into first half's MFMA)
#pragma unroll
    for (int k0 = 4; k0 < 8; ++k0) {
      bf16x8 a[4];
#pragma unroll
      for (int rt = 0; rt < 4; ++rt)
        a[rt] = *(const bf16x8*)(Vb + (size_t)(rb0 + rt * 16 + lo) * 256 + k0 * 32 + hi * 8);
#pragma unroll
      for (int ct = 0; ct < 8; ++ct) {
        bf16x8 bb = *(const bf16x8*)(smem + swz(d0 + ct * 16 + lo, (k0 * 32 + hi * 8) * 2));
#pragma unroll
        for (int rt = 0; rt < 4; ++rt) acc[rt][ct] = MFMA16(a[rt], bb, acc[rt][ct]);
      }
    }
    float* ob = out + (size_t)b * 65536;
#pragma unroll
    for (int rt = 0; rt < 4; ++rt)
#pragma unroll
      for (int reg = 0; reg < 4; ++reg) {
        const int c = rb0 + rt * 16 + hi * 4 + reg;
#pragma unroll
        for (int ct = 0; ct < 8; ++ct) {
          const int d = d0 + ct * 16 + lo;
          const int idx = c * 256 + d;
          ob[idx] = acc[rt][ct][reg] + bf2f(xhb[idx]);
        }
      }
  }
}

// ---------------------------------------------------------------------------
extern "C" void kernel_launch(void* const* d_in, const int* in_sizes, int n_in,
                              void* d_out, int out_size, void* d_ws, size_t ws_size,
                              hipStream_t stream) {
  const float* x = (const float*)d_in[0];
  const float* Wq = (const float*)d_in[1];
  const float* bq = (const float*)d_in[2];
  const float* Wk = (const float*)d_in[3];
  const float* bk = (const float*)d_in[4];
  const float* Wv = (const float*)d_in[5];
  const float* bv = (const float*)d_in[6];
  const float* gamma = (const float*)d_in[7];
  float* out = (float*)d_out;

  unsigned short* Y = (unsigned short*)d_ws;                 // 384 MiB
  unsigned short* xh = Y + (size_t)1024 * 196608;            // 128 MiB
  unsigned short* W3h = xh + (size_t)1024 * 65536;           // 384 KiB
  float* b3 = (float*)(W3h + 768 * 256);                     // 3 KiB
  const size_t need =
      ((size_t)1024 * 196608 + (size_t)1024 * 65536 + 768 * 256) * 2 + 768 * 4;
  if (ws_size < need) return;  // ~512.4 MiB

  hipLaunchKernelGGL(k_prep, dim3(768), dim3(256), 0, stream,
                     Wq, bq, Wk, bk, Wv, bv, gamma, W3h, b3);
  hipLaunchKernelGGL(k_gemm2, dim3(12288), dim3(256), 0, stream, W3h, b3, x, Y, xh);
  hipLaunchKernelGGL(attn5, dim3(1024), dim3(512), 0, stream, xh, Y, out);
}

// Round 16
// 507.441 us; speedup vs baseline: 1.8458x; 1.0562x over previous
//
#include <hip/hip_runtime.h>

// ---------------------------------------------------------------------------
// SelfAttention: B=1024, C=N=256.
//   Q=(WqX+bq)/16 ; K=WkX+bk ; Vg=gamma*(WvX+bv) ; P=softmax_rows(Q K^T);
//   out = Vg P + x
// R16 = R8 configuration restored verbatim (measured session best: 510 us).
//   k_prep  : W3h[768][256] = bf16(scale_p * W_p), b3[768]
//   k_gemm2 : Y = W3h * X^T + b3, batch-major [b][3][256][256]; fused x
//             transpose; x loads live only load->TS-store within a chunk.
//   attn5   : single-pass fused attention + V-half-prefetch; f32 x residual
//             (x is L3-warm from gemm2's streaming).
// ---------------------------------------------------------------------------

typedef __attribute__((ext_vector_type(8))) short bf16x8;
typedef __attribute__((ext_vector_type(4))) short bf16x4;
typedef __attribute__((ext_vector_type(4))) float f32x4;

#define MFMA16(a, b, c) __builtin_amdgcn_mfma_f32_16x16x32_bf16((a), (b), (c), 0, 0, 0)

#define GLDS16(g, l)                                                      \
  __builtin_amdgcn_global_load_lds(                                       \
      (const __attribute__((address_space(1))) void*)(g),                 \
      (__attribute__((address_space(3))) void*)(l), 16, 0, 0)

static __device__ __forceinline__ unsigned short f2bf(float f) {
  unsigned int u = __float_as_uint(f);
  u += 0x7fffu + ((u >> 16) & 1u);  // round-to-nearest-even
  return (unsigned short)(u >> 16);
}

// rows x 512B swizzled LDS buffer; XOR spreads stride-512B accesses.
static __device__ __forceinline__ int swz(int row, int byteInRow) {
  return row * 512 + (byteInRow ^ ((row & 7) << 4));
}

// ---------------------------------------------------------------------------
// Kernel 0: stacked scaled weights + biases.
// ---------------------------------------------------------------------------
__global__ void k_prep(const float* __restrict__ Wq, const float* __restrict__ bq,
                       const float* __restrict__ Wk, const float* __restrict__ bk,
                       const float* __restrict__ Wv, const float* __restrict__ bv,
                       const float* __restrict__ gamma,
                       unsigned short* __restrict__ W3h, float* __restrict__ b3) {
  const int r = blockIdx.x;  // 0..767
  const int p = r >> 8, sr = r & 255;
  const float s = (p == 0) ? 0.0625f : (p == 1 ? 1.0f : gamma[0]);
  const float* W = (p == 0) ? Wq : (p == 1 ? Wk : Wv);
  const float* bs = (p == 0) ? bq : (p == 1 ? bk : bv);
  W3h[r * 256 + threadIdx.x] = f2bf(W[sr * 256 + threadIdx.x] * s);
  if (threadIdx.x == 0) b3[r] = bs[sr] * s;
}

// ---------------------------------------------------------------------------
// Kernel 1: flat GEMM with fused transpose.
//   Y[m][b*256+n] = sum_i W3h[m][i] * x[b][i][n] + b3[m]
//   128x128 tile, BK=64, 256 threads, LDS: A 16K | B 16K | TS 17K = 49K
//   A staged via global_load_lds (swizzled source); B staged per 64x64
//   chunk: x f32 load -> immediate TS write -> transposed cvt -> swizzled B.
// ---------------------------------------------------------------------------
__global__ __launch_bounds__(256, 3) void k_gemm2(
    const unsigned short* __restrict__ W3h, const float* __restrict__ b3,
    const float* __restrict__ x, unsigned short* __restrict__ Y) {
  __shared__ char smem[50176];
  float* TS = (float*)(smem + 32768);
  const int bid = blockIdx.x;
  const int swzb = (bid & 7) * 1536 + (bid >> 3);
  const int r_t = swzb % 6, bn_t = swzb / 6;
  const int m0 = r_t * 128, n0 = bn_t * 128;
  const int bb = n0 >> 8, nl0 = n0 & 255;
  const float* xb = x + (size_t)bb * 65536;
  const int tid = threadIdx.x, wv = tid >> 6, lane = tid & 63;
  const int lo = lane & 15, hi = lane >> 4;
  const int wm = wv >> 1, wn = wv & 1;
  const int tr = tid >> 4, tc = (tid & 15) * 4;  // staging row/col

  f32x4 acc[4][4];
#pragma unroll
  for (int i = 0; i < 4; ++i)
#pragma unroll
    for (int j = 0; j < 4; ++j) acc[i][j] = (f32x4){0.f, 0.f, 0.f, 0.f};

  for (int k0 = 0; k0 < 256; k0 += 64) {
    // ---- A tile via GLDS (async, drained by first barrier below) ----
#pragma unroll
    for (int j = 0; j < 4; ++j) {
      const int s = j * 256 + tid;
      const int row = s >> 3, gs = (s & 7) ^ (row & 7);
      GLDS16(W3h + (size_t)(m0 + row) * 256 + k0 + gs * 8,
             smem + j * 4096 + wv * 1024);
    }

    // ---- B staging: two 64x64 transpose chunks through TS ----
#pragma unroll
    for (int c = 0; c < 2; ++c) {
      if (c == 1) __syncthreads();  // chunk0 TS reads done before overwrite
      // load this chunk's x and write straight to TS (no barrier-crossing regs)
#pragma unroll
      for (int j = 0; j < 4; ++j) {
        float4 xg = *(const float4*)(xb + (k0 + tr + j * 16) * 256 + nl0 + c * 64 + tc);
        *(float4*)(&TS[(tr + j * 16) * 68 + tc]) = xg;
      }
      __syncthreads();  // TS visible
#pragma unroll
      for (int ff = 0; ff < 2; ++ff) {
        const int g = wv + ff * 4;  // k-granule 0..7
        const int n = lane;
        bf16x8 v;
#pragma unroll
        for (int j = 0; j < 8; ++j) v[j] = (short)f2bf(TS[(g * 8 + j) * 68 + n]);
        const int row = c * 64 + n;
        *(bf16x8*)(smem + 16384 + row * 128 + ((g ^ (row & 7)) * 16)) = v;
      }
    }
    __syncthreads();  // B-tile writes visible (A-tile long drained)

    // ---- MFMA ----
#pragma unroll
    for (int kk = 0; kk < 2; ++kk) {
      bf16x8 a[4], b[4];
#pragma unroll
      for (int rt = 0; rt < 4; ++rt) {
        const int row = wm * 64 + rt * 16 + lo, g = kk * 4 + hi;
        a[rt] = *(const bf16x8*)(smem + row * 128 + ((g ^ (row & 7)) * 16));
      }
#pragma unroll
      for (int ct = 0; ct < 4; ++ct) {
        const int row = wn * 64 + ct * 16 + lo, g = kk * 4 + hi;
        b[ct] = *(const bf16x8*)(smem + 16384 + row * 128 + ((g ^ (row & 7)) * 16));
      }
#pragma unroll
      for (int rt = 0; rt < 4; ++rt)
#pragma unroll
        for (int ct = 0; ct < 4; ++ct) acc[rt][ct] = MFMA16(a[rt], b[ct], acc[rt][ct]);
    }
    __syncthreads();  // MFMA reads done before next k0 overwrite
  }

  // Epilogue: bias, bf16, swizzled-LDS repack, coalesced 16B batch-major stores.
  float b3v[4][4];
#pragma unroll
  for (int rt = 0; rt < 4; ++rt)
#pragma unroll
    for (int reg = 0; reg < 4; ++reg)
      b3v[rt][reg] = b3[m0 + wm * 64 + rt * 16 + hi * 4 + reg];
#pragma unroll
  for (int rt = 0; rt < 4; ++rt)
#pragma unroll
    for (int ct = 0; ct < 4; ++ct)
#pragma unroll
      for (int reg = 0; reg < 4; ++reg) {
        const int m = wm * 64 + rt * 16 + hi * 4 + reg;
        const int n = wn * 64 + ct * 16 + lo;
        *(unsigned short*)(smem + m * 256 + ((n * 2) ^ ((m & 7) << 4))) =
            f2bf(acc[rt][ct][reg] + b3v[rt][reg]);
      }
  __syncthreads();
  const int p = m0 >> 8, sr0 = m0 & 255;
  unsigned short* dstb = Y + (size_t)bb * 196608 + (size_t)p * 65536;
#pragma unroll
  for (int j = 0; j < 8; ++j) {
    const int s = j * 256 + tid;
    const int m = s >> 4, pp = s & 15;
    const int ng = pp ^ (m & 7);
    int4 v = *(const int4*)(smem + m * 256 + pp * 16);
    *(int4*)(dstb + (size_t)(sr0 + m) * 256 + nl0 + ng * 8) = v;
  }
}

// ---------------------------------------------------------------------------
// Kernel 2: single-pass fused attention (128 KB LDS, 1 block/CU).
//   K staged once via global_load_lds; Q prefetched to regs during staging;
//   V half-prefetched under the softmax shadow; max-skip softmax;
//   P^T -> LDS (overwrites K); O full-width + residual.
// ---------------------------------------------------------------------------
__global__ __launch_bounds__(512, 2) void attn5(
    const float* __restrict__ x, const unsigned short* __restrict__ Y,
    float* __restrict__ out) {
  __shared__ char smem[131072];  // 256 rows x 512 B
  const int b = blockIdx.x;
  const float* xb = x + (size_t)b * 65536;
  const unsigned short* Qb = Y + (size_t)b * 196608;
  const unsigned short* Kb = Qb + 65536;
  const unsigned short* Vb = Qb + 131072;
  const int tid = threadIdx.x, w = tid >> 6, lane = tid & 63;
  const int lo = lane & 15, hi = lane >> 4;
  const int r0 = w * 32;
  const int rb0 = (w >> 1) * 64, d0 = (w & 1) * 128;

  // ---- issue async K stage (linear LDS dest, inverse-swizzled source) ----
#pragma unroll
  for (int i = 0; i < 16; ++i) {
    const int idx = i * 512 + tid;  // 16B granules, 0..8191
    const int row = idx >> 5, c16 = idx & 31;
    const int gs = (c16 & 24) | ((c16 ^ row) & 7);
    GLDS16(Kb + (size_t)row * 256 + gs * 8, smem + idx * 16);
  }
  // ---- concurrently prefetch this wave's Q fragments into registers ----
  bf16x8 aq[2][8];
#pragma unroll
  for (int k0 = 0; k0 < 8; ++k0)
#pragma unroll
    for (int rt = 0; rt < 2; ++rt)
      aq[rt][k0] =
          *(const bf16x8*)(Qb + (size_t)(r0 + rt * 16 + lo) * 256 + k0 * 32 + hi * 8);
  __syncthreads();

  bf16x8 av[4][4];  // V prefetch (k = 0..127), issued under softmax shadow

  // ---- Phase A: S = Q K^T (regs x LDS); p=exp(S); normalize; P^T -> LDS ----
  {
    f32x4 acc[2][16];
#pragma unroll
    for (int i = 0; i < 2; ++i)
#pragma unroll
      for (int j = 0; j < 16; ++j) acc[i][j] = (f32x4){0.f, 0.f, 0.f, 0.f};
#pragma unroll
    for (int k0 = 0; k0 < 8; ++k0)
#pragma unroll
      for (int ct = 0; ct < 16; ++ct) {
        bf16x8 bb = *(const bf16x8*)(smem + swz(ct * 16 + lo, (k0 * 32 + hi * 8) * 2));
        acc[0][ct] = MFMA16(aq[0][k0], bb, acc[0][ct]);
        acc[1][ct] = MFMA16(aq[1][k0], bb, acc[1][ct]);
      }
    // V half-prefetch: HBM stays busy under the softmax + P^T write + barrier
#pragma unroll
    for (int kq = 0; kq < 4; ++kq)
#pragma unroll
      for (int rt = 0; rt < 4; ++rt)
        av[rt][kq] =
            *(const bf16x8*)(Vb + (size_t)(rb0 + rt * 16 + lo) * 256 + kq * 32 + hi * 8);
    // max-skip softmax: p = exp(S); row-sum over 16 ct + 16 lo-lanes
#pragma unroll
    for (int rt = 0; rt < 2; ++rt)
#pragma unroll
      for (int reg = 0; reg < 4; ++reg) {
        float s = 0.f;
        float vals[16];
#pragma unroll
        for (int ct = 0; ct < 16; ++ct) {
          const float p = __expf(acc[rt][ct][reg]);
          vals[ct] = p;
          s += p;
        }
        s += __shfl_xor(s, 1);
        s += __shfl_xor(s, 2);
        s += __shfl_xor(s, 4);
        s += __shfl_xor(s, 8);
        const float inv = 1.0f / s;
#pragma unroll
        for (int ct = 0; ct < 16; ++ct) acc[rt][ct][reg] = vals[ct] * inv;
      }
    __syncthreads();  // all K reads done before overwrite
#pragma unroll
    for (int rt = 0; rt < 2; ++rt)
#pragma unroll
      for (int ct = 0; ct < 16; ++ct) {
        const int d = ct * 16 + lo;
        const int s0 = r0 + rt * 16 + hi * 4;
        bf16x4 v;
#pragma unroll
        for (int reg = 0; reg < 4; ++reg) v[reg] = (short)f2bf(acc[rt][ct][reg]);
        *(bf16x4*)(smem + swz(d, s0 * 2)) = v;
      }
  }
  __syncthreads();

  // ---- Phase B: O = V P ; out = O + x ----
  {
    f32x4 acc[4][8];
#pragma unroll
    for (int i = 0; i < 4; ++i)
#pragma unroll
      for (int j = 0; j < 8; ++j) acc[i][j] = (f32x4){0.f, 0.f, 0.f, 0.f};
    // first half: V from prefetched registers
#pragma unroll
    for (int k0 = 0; k0 < 4; ++k0)
#pragma unroll
      for (int ct = 0; ct < 8; ++ct) {
        bf16x8 bb = *(const bf16x8*)(smem + swz(d0 + ct * 16 + lo, (k0 * 32 + hi * 8) * 2));
#pragma unroll
        for (int rt = 0; rt < 4; ++rt) acc[rt][ct] = MFMA16(av[rt][k0], bb, acc[rt][ct]);
      }
    // second half: V loaded in-loop (compiler hoists into first half's MFMA)
#pragma unroll
    for (int k0 = 4; k0 < 8; ++k0) {
      bf16x8 a[4];
#pragma unroll
      for (int rt = 0; rt < 4; ++rt)
        a[rt] = *(const bf16x8*)(Vb + (size_t)(rb0 + rt * 16 + lo) * 256 + k0 * 32 + hi * 8);
#pragma unroll
      for (int ct = 0; ct < 8; ++ct) {
        bf16x8 bb = *(const bf16x8*)(smem + swz(d0 + ct * 16 + lo, (k0 * 32 + hi * 8) * 2));
#pragma unroll
        for (int rt = 0; rt < 4; ++rt) acc[rt][ct] = MFMA16(a[rt], bb, acc[rt][ct]);
      }
    }
    float* ob = out + (size_t)b * 65536;
#pragma unroll
    for (int rt = 0; rt < 4; ++rt)
#pragma unroll
      for (int reg = 0; reg < 4; ++reg) {
        const int c = rb0 + rt * 16 + hi * 4 + reg;
#pragma unroll
        for (int ct = 0; ct < 8; ++ct) {
          const int d = d0 + ct * 16 + lo;
          const int idx = c * 256 + d;
          ob[idx] = acc[rt][ct][reg] + xb[idx];
        }
      }
  }
}

// ---------------------------------------------------------------------------
extern "C" void kernel_launch(void* const* d_in, const int* in_sizes, int n_in,
                              void* d_out, int out_size, void* d_ws, size_t ws_size,
                              hipStream_t stream) {
  const float* x = (const float*)d_in[0];
  const float* Wq = (const float*)d_in[1];
  const float* bq = (const float*)d_in[2];
  const float* Wk = (const float*)d_in[3];
  const float* bk = (const float*)d_in[4];
  const float* Wv = (const float*)d_in[5];
  const float* bv = (const float*)d_in[6];
  const float* gamma = (const float*)d_in[7];
  float* out = (float*)d_out;

  unsigned short* Y = (unsigned short*)d_ws;                 // 384 MiB
  unsigned short* W3h = Y + (size_t)1024 * 196608;           // 384 KiB
  float* b3 = (float*)(W3h + 768 * 256);                     // 3 KiB
  const size_t need = ((size_t)1024 * 196608 + 768 * 256) * 2 + 768 * 4;
  if (ws_size < need) return;

  hipLaunchKernelGGL(k_prep, dim3(768), dim3(256), 0, stream,
                     Wq, bq, Wk, bk, Wv, bv, gamma, W3h, b3);
  hipLaunchKernelGGL(k_gemm2, dim3(12288), dim3(256), 0, stream, W3h, b3, x, Y);
  hipLaunchKernelGGL(attn5, dim3(1024), dim3(512), 0, stream, x, Y, out);
}